// Round 4
// baseline (41250.027 us; speedup 1.0000x reference)
//
#include <hip/hip_runtime.h>

// CVRAE forward — weight-stationary XCD column partitioning, v2.
// B=256, S=512, A=64, H=1024, Z=256. NWG=256 (1 WG/CU, 32 WGs/XCD).
//
// Structure per step (2 GLOBAL + 2 per-XCD barriers; was 4 global):
//   P1 : hidcat cols [g*256) + gate cols 3x[g*128)  (global h in, agent out)
//   -- global barrier --
//   P2r: z computed REDUNDANTLY per XCD (full 256x256) -> zloc (local L2);
//        prior logits + kld only for own z-slice [g*32) (exact, balanced)
//   -- per-XCD barrier --
//   P3r: pz computed REDUNDANTLY per XCD (full 256x1024) -> pzloc (local L2)
//   -- per-XCD barrier --
//   P4 : GRU gates for j in [g*128): gh/hf local, h_new agent-stored
//   -- global barrier --
// All MFMA use SWAPPED operands mfma(W_frag, A_frag): thread holds 4
// CONSECUTIVE output cols of one row -> 8B packed bf16x4 stores and float4
// bias/gh/gipx/hf accesses (R3 used scalar 2B stores). Global barrier flag is
// broadcast to 8 per-XCD lines (32 pollers/line, was 256 on one line).

typedef float f32x4 __attribute__((ext_vector_type(4)));
typedef __bf16 bf16x8 __attribute__((ext_vector_type(8)));
typedef unsigned long long u64;

#define BB 256
#define SS 512
#define HH 1024
#define ZZ 256
#define AA 64
#define NWG 256
#define MFMA __builtin_amdgcn_mfma_f32_16x16x32_bf16

__device__ __forceinline__ float softplus_(float x) {
    return (x > 15.f) ? x : log1pf(expf(x));
}
__device__ __forceinline__ float sigmoid_(float x) {
    return 1.f / (1.f + expf(-x));
}

// ---- agent-scope (LLC coherence point) helpers ----
__device__ __forceinline__ u64 ld8a(const void* p) {
    return __hip_atomic_load((const u64*)p, __ATOMIC_RELAXED, __HIP_MEMORY_SCOPE_AGENT);
}
__device__ __forceinline__ void st8a(void* p, u64 v) {
    __hip_atomic_store((u64*)p, v, __ATOMIC_RELAXED, __HIP_MEMORY_SCOPE_AGENT);
}
__device__ __forceinline__ u64 pack4bf(float a0, float a1, float a2, float a3) {
    union { __bf16 h[4]; u64 w; } pk;
    pk.h[0] = (__bf16)a0; pk.h[1] = (__bf16)a1;
    pk.h[2] = (__bf16)a2; pk.h[3] = (__bf16)a3;
    return pk.w;
}

// ---- relaxed-tree global barrier, per-XCD broadcast flags ----
__device__ __forceinline__ void gbarG(unsigned* bar, unsigned p, int wg, int g) {
    __syncthreads();
    if (threadIdx.x == 0) {
        unsigned s = p & 7u;
        unsigned exp = (p >> 3) + 1u;
        unsigned* leaf = bar + (s * 8 + (wg >> 5)) * 16;
        unsigned* root = bar + (64 + s) * 16;
        unsigned* flag = bar + (128 + (s * 8 + g)) * 16;
        unsigned old = __hip_atomic_fetch_add(leaf, 1u, __ATOMIC_RELAXED, __HIP_MEMORY_SCOPE_AGENT);
        if (old == 32u * exp - 1u) {
            unsigned old2 = __hip_atomic_fetch_add(root, 1u, __ATOMIC_RELAXED, __HIP_MEMORY_SCOPE_AGENT);
            if (old2 == 8u * exp - 1u) {
                #pragma unroll
                for (int gg = 0; gg < 8; gg++)
                    __hip_atomic_store(bar + (128 + (s * 8 + gg)) * 16, exp,
                                       __ATOMIC_RELAXED, __HIP_MEMORY_SCOPE_AGENT);
            }
        }
        while (__hip_atomic_load(flag, __ATOMIC_RELAXED, __HIP_MEMORY_SCOPE_AGENT) < exp)
            __builtin_amdgcn_s_sleep(2);
    }
    asm volatile("buffer_inv sc0" ::: "memory");
    __syncthreads();
}

// ---- per-XCD barrier ----
__device__ __forceinline__ void xbar(unsigned* flags, int g, int rank, int ngrp,
                                     unsigned tok) {
    __syncthreads();
    if (threadIdx.x == 0)
        __hip_atomic_store(flags + g * 256 + rank, tok, __ATOMIC_RELAXED,
                           __HIP_MEMORY_SCOPE_AGENT);
    unsigned l = threadIdx.x & 63;
    unsigned* base = flags + g * 256;
    for (;;) {
        bool ok = true;
        for (int i = (int)l; i < ngrp; i += 64)
            ok &= (__hip_atomic_load(base + i, __ATOMIC_RELAXED,
                                     __HIP_MEMORY_SCOPE_AGENT) >= tok);
        if (__all(ok)) break;
        __builtin_amdgcn_s_sleep(2);
    }
    asm volatile("buffer_inv sc0" ::: "memory");
    __syncthreads();
}

// ---------------- wave GEMM helper (tail only) ----------------
template<int MT, int NT>
__device__ __forceinline__ void wgemm(const __bf16* __restrict__ A, int lda, int mstride,
                                      const __bf16* __restrict__ B, int ldb, int nstride,
                                      int K, f32x4 (&acc)[MT][NT]) {
    int lane = threadIdx.x & 63;
    int rr = lane & 15;
    int ko = (lane >> 4) * 8;
    const __bf16* ap = A + rr * lda + ko;
    const __bf16* bp = B + rr * ldb + ko;
    #pragma unroll 2
    for (int k = 0; k < K; k += 32) {
        bf16x8 af[MT], bfr[NT];
        #pragma unroll
        for (int mt = 0; mt < MT; mt++) af[mt] = *(const bf16x8*)(ap + mt * mstride + k);
        #pragma unroll
        for (int nt = 0; nt < NT; nt++) bfr[nt] = *(const bf16x8*)(bp + nt * nstride + k);
        #pragma unroll
        for (int mt = 0; mt < MT; mt++)
            #pragma unroll
            for (int nt = 0; nt < NT; nt++)
                acc[mt][nt] = MFMA(af[mt], bfr[nt], acc[mt][nt], 0, 0, 0);
    }
}

// ---------------- prep kernels ----------------

__global__ void k_zeroctl(unsigned* bar, unsigned* flags, unsigned* cnt, float* kldacc) {
    for (int i = threadIdx.x; i < 4096; i += 256) bar[i] = 0u;
    for (int i = threadIdx.x; i < 2048; i += 256) flags[i] = 0u;
    if (threadIdx.x < 8) cnt[threadIdx.x] = 0u;
    if (threadIdx.x == 0) *kldacc = 0.f;
}

__global__ void k_pack(const float* __restrict__ src, int src_ld, int col_off,
                       __bf16* __restrict__ dst, int cols, int total) {
    int i = blockIdx.x * 256 + threadIdx.x;
    if (i >= total) return;
    int r = i / cols, c = i - r * cols;
    dst[i] = (__bf16)src[r * src_ld + col_off + c];
}

__global__ void k_copyf(const float* __restrict__ s, float* __restrict__ d, int n) {
    int i = blockIdx.x * 256 + threadIdx.x;
    if (i < n) d[i] = s[i];
}

__global__ void k_px(const float* __restrict__ phi_x_w, const float* __restrict__ phi_x_b,
                     float* __restrict__ px) {
    int i = blockIdx.x * 256 + threadIdx.x;  // 64*1024
    int a = i >> 10, hh = i & 1023;
    px[i] = fmaxf(phi_x_w[hh * AA + a] + phi_x_b[hh], 0.f);
}

__global__ __launch_bounds__(256) void k_tables(const float* __restrict__ enc_w1,
                                                const float* __restrict__ wih,
                                                const float* __restrict__ px,
                                                float* __restrict__ encpx,
                                                float* __restrict__ gipx) {
    __shared__ float spx[64][65];
    int tid = threadIdx.x;
    int cg = blockIdx.x * 4 + (tid >> 6);
    int a = tid & 63;
    const float* wrow = (cg < 1024) ? (enc_w1 + cg * 2048) : (wih + (cg - 1024) * 2048);
    float sum = 0.f;
    for (int k0 = 0; k0 < 1024; k0 += 64) {
        __syncthreads();
        for (int e = tid; e < 4096; e += 256)
            spx[e >> 6][e & 63] = px[((e >> 6) << 10) + k0 + (e & 63)];
        __syncthreads();
        #pragma unroll 8
        for (int kk = 0; kk < 64; kk++) sum += wrow[k0 + kk] * spx[a][kk];
    }
    if (cg < 1024) encpx[a * 1024 + cg] = sum;
    else gipx[a * 3072 + (cg - 1024)] = sum;
}

// ---------------- persistent kernel ----------------

struct PArgs {
    const int* x; const float* eps;
    const __bf16 *WA, *W2, *WPZ, *WIH, *WHH, *WDEC, *WACT;
    const float *encpx, *gipx;
    const float *eb1, *pb1, *eb2, *pb2, *pzb, *decb, *actb, *bih, *bhh;
    float *hf0, *hf1; __bf16 *hb0, *hb1;
    __bf16 *hidcat, *zbuf, *pzbuf, *tailhid, *decbuf;
    __bf16 *zloc8, *pzloc8;
    float *gh; float *kldacc; unsigned *bar, *flags, *cnt;
    float* out;
};

__global__ __launch_bounds__(256, 1) void k_persist(PArgs a) {
    int wg = blockIdx.x;
    int tid = threadIdx.x;
    int v = tid >> 6;                // wave in WG
    int lane = tid & 63;
    int rr = lane & 15;              // fragment row (within-tile)
    int ko = (lane >> 4) * 8;        // fragment k-offset
    int col = lane & 15;             // swapped-mode: batch row within m-tile
    int rq = (lane >> 4) * 4;        // swapped-mode: first of 4 consecutive out cols
    float kl = 0.f;
    float* hf[2] = {a.hf0, a.hf1};
    __bf16* hb[2] = {a.hb0, a.hb1};

    // row len 2056: 16B-aligned rows, bank stride 1028%32=4 -> 2-way (free)
    __shared__ __align__(16) __bf16 Alds[16][2056];
    __shared__ int sh_g, sh_rank, sh_ngrp;
    __shared__ float sh_kl[4];

    if (tid == 0) {
        unsigned xcc = __builtin_amdgcn_s_getreg((31 << 11) | (0 << 6) | 20) & 7u;
        sh_g = (int)xcc;
        sh_rank = (int)atomicAdd(a.cnt + xcc, 1u);
    }
    __syncthreads();
    int g = sh_g, rank = sh_rank;
    gbarG(a.bar, 0, wg, g);
    if (tid == 0)
        sh_ngrp = (int)__hip_atomic_load(a.cnt + g, __ATOMIC_RELAXED,
                                         __HIP_MEMORY_SCOPE_AGENT);
    __syncthreads();
    int ngrp = sh_ngrp;
    int base_m = g * 32;                       // tail batch slice
    __bf16* zloc = a.zloc8 + (size_t)g * BB * ZZ;
    __bf16* pzloc = a.pzloc8 + (size_t)g * BB * HH;

    unsigned gp = 1;       // global barrier phase
    unsigned tok = 1;      // per-XCD barrier token

    for (int t = 0; t < SS; t++) {
        int cur = t & 1, nxt = cur ^ 1;

        // ==== P1: 40 n-tiles owned by XCD g (16 enc-or-pri + 24 gate), all
        //     256 rows. WG = (m-tile, half); A (h) staged to LDS via agent. ====
        for (int r0 = rank; r0 < 32; r0 += ngrp) {
            int mt = r0 & 15, half = r0 >> 4;
            __syncthreads();
            {
                const __bf16* src = hb[cur] + (size_t)(mt * 16) * HH + tid * 4;
                u64 tmp[16];
                #pragma unroll
                for (int e = 0; e < 16; e++) tmp[e] = ld8a(src + (size_t)e * HH);
                #pragma unroll
                for (int e = 0; e < 16; e++) *(u64*)(&Alds[e][tid * 4]) = tmp[e];
            }
            __syncthreads();
            int ntg = half * 4 + v;            // 0..7
            const __bf16* bp[5]; int qv[5];
            #pragma unroll
            for (int j = 0; j < 5; j++) {
                int q = ntg * 5 + j; qv[j] = q;
                const __bf16* b;
                if (q < 16) b = a.WA + (size_t)(g * 256 + q * 16 + rr) * HH;
                else {
                    int qq = q - 16;
                    b = a.WHH + (size_t)((qq >> 3) * 1024 + g * 128 + (qq & 7) * 16 + rr) * HH;
                }
                bp[j] = b + ko;
            }
            f32x4 acc[5] = {};
            const __bf16* arow = &Alds[rr][ko];
            #pragma unroll 4
            for (int k = 0; k < HH; k += 32) {
                bf16x8 af = *(const bf16x8*)(arow + k);
                #pragma unroll
                for (int j = 0; j < 5; j++)
                    acc[j] = MFMA(*(const bf16x8*)(bp[j] + k), af, acc[j], 0, 0, 0);
            }
            // swapped: thread holds row m = mt*16+col, cols base+rq..+3
            int m = mt * 16 + col;
            #pragma unroll
            for (int j = 0; j < 5; j++) {
                int q = qv[j];
                if (q < 16) {
                    int c = g * 256 + q * 16 + rq;
                    if (c < 1024) {
                        int xb = a.x[m * SS + t];
                        f32x4 bias = *(const f32x4*)(a.eb1 + c);
                        f32x4 ep = *(const f32x4*)(a.encpx + (size_t)xb * 1024 + c);
                        st8a(&a.hidcat[(size_t)m * 2048 + c],
                             pack4bf(fmaxf(acc[j][0] + bias[0] + ep[0], 0.f),
                                     fmaxf(acc[j][1] + bias[1] + ep[1], 0.f),
                                     fmaxf(acc[j][2] + bias[2] + ep[2], 0.f),
                                     fmaxf(acc[j][3] + bias[3] + ep[3], 0.f)));
                    } else {
                        f32x4 bias = *(const f32x4*)(a.pb1 + (c - 1024));
                        st8a(&a.hidcat[(size_t)m * 2048 + c],
                             pack4bf(fmaxf(acc[j][0] + bias[0], 0.f),
                                     fmaxf(acc[j][1] + bias[1], 0.f),
                                     fmaxf(acc[j][2] + bias[2], 0.f),
                                     fmaxf(acc[j][3] + bias[3], 0.f)));
                    }
                } else {
                    int qq = q - 16;
                    int gc = (qq >> 3) * 1024 + g * 128 + (qq & 7) * 16 + rq;
                    f32x4 w = {acc[j][0], acc[j][1], acc[j][2], acc[j][3]};
                    *(f32x4*)(a.gh + (size_t)m * 3072 + gc) = w;   // local
                }
            }
        }
        gbarG(a.bar, gp++, wg, g);

        // ==== P2r: full z (256x256) redundantly per XCD -> zloc (local).
        //     prior/kld only for own z-slice (zt>>1 == g): exact + balanced. ====
        for (int r0 = rank; r0 < 32; r0 += ngrp) {
            int mt = r0 & 15, zh = r0 >> 4;
            __syncthreads();
            {
                const __bf16* src = a.hidcat + (size_t)(mt * 16) * 2048 + tid * 4;
                u64 t0[16], t1[16];
                #pragma unroll
                for (int e = 0; e < 16; e++) t0[e] = ld8a(src + (size_t)e * 2048);
                #pragma unroll
                for (int e = 0; e < 16; e++) t1[e] = ld8a(src + 1024 + (size_t)e * 2048);
                #pragma unroll
                for (int e = 0; e < 16; e++) {
                    *(u64*)(&Alds[e][tid * 4]) = t0[e];
                    *(u64*)(&Alds[e][1024 + tid * 4]) = t1[e];
                }
            }
            __syncthreads();
            const __bf16* arow = &Alds[rr][ko];
            #pragma unroll
            for (int zz = 0; zz < 2; zz++) {
                int zt = zh * 8 + v * 2 + zz;
                const __bf16* be = a.W2 + (size_t)(zt * 16 + rr) * HH + ko;
                f32x4 ae = {0.f, 0.f, 0.f, 0.f};
                #pragma unroll 4
                for (int k = 0; k < HH; k += 32)
                    ae = MFMA(*(const bf16x8*)(be + k), *(const bf16x8*)(arow + k), ae, 0, 0, 0);
                int m = mt * 16 + col;
                int z = zt * 16 + rq;
                f32x4 b_e = *(const f32x4*)(a.eb2 + z);
                const float* epst = a.eps + (size_t)t * BB * ZZ + (size_t)m * ZZ + z;
                union { u64 w; float f[2]; } u0, u1;
                u0.w = ld8a(epst); u1.w = ld8a(epst + 2);
                float ef[4] = {u0.f[0], u0.f[1], u1.f[0], u1.f[1]};
                float enc[4], es[4];
                #pragma unroll
                for (int i = 0; i < 4; i++) {
                    enc[i] = ae[i] + b_e[i];
                    es[i] = softplus_(enc[i]);
                }
                if ((zt >> 1) == g) {   // own slice: prior + kld
                    const __bf16* bpr = a.W2 + (size_t)(256 + zt * 16 + rr) * HH + ko;
                    f32x4 av = {0.f, 0.f, 0.f, 0.f};
                    #pragma unroll 4
                    for (int k = 0; k < HH; k += 32)
                        av = MFMA(*(const bf16x8*)(bpr + k),
                                  *(const bf16x8*)(arow + 1024 + k), av, 0, 0, 0);
                    f32x4 b_p = *(const f32x4*)(a.pb2 + z);
                    #pragma unroll
                    for (int i = 0; i < 4; i++) {
                        float pri = av[i] + b_p[i];
                        float ps = softplus_(pri);
                        float d = enc[i] - pri;
                        kl += 2.f * (logf(ps) - logf(es[i]))
                              + (es[i] * es[i] + d * d) / (ps * ps) - 1.f;
                    }
                }
                *(u64*)(zloc + (size_t)m * ZZ + z) =
                    pack4bf(ef[0] * es[0] + enc[0], ef[1] * es[1] + enc[1],
                            ef[2] * es[2] + enc[2], ef[3] * es[3] + enc[3]);
            }
        }
        xbar(a.flags, g, rank, ngrp, tok++);

        // ==== P3r: full pz (256x1024) redundantly per XCD -> pzloc (local). ====
        for (int r0 = rank; r0 < 32; r0 += ngrp) {
            int mt = r0 & 15, nh = r0 >> 4;
            const __bf16* az = zloc + (size_t)(mt * 16 + rr) * ZZ + ko;
            int nt0 = nh * 32 + v * 8;
            const __bf16* bwz[8];
            #pragma unroll
            for (int j = 0; j < 8; j++)
                bwz[j] = a.WPZ + (size_t)((nt0 + j) * 16 + rr) * ZZ + ko;
            f32x4 acc[8] = {};
            #pragma unroll
            for (int k = 0; k < ZZ; k += 32) {
                bf16x8 af = *(const bf16x8*)(az + k);
                #pragma unroll
                for (int j = 0; j < 8; j++)
                    acc[j] = MFMA(*(const bf16x8*)(bwz[j] + k), af, acc[j], 0, 0, 0);
            }
            int m = mt * 16 + col;
            #pragma unroll
            for (int j = 0; j < 8; j++) {
                int n = (nt0 + j) * 16 + rq;
                f32x4 bb = *(const f32x4*)(a.pzb + n);
                *(u64*)(pzloc + (size_t)m * HH + n) =
                    pack4bf(fmaxf(acc[j][0] + bb[0], 0.f), fmaxf(acc[j][1] + bb[1], 0.f),
                            fmaxf(acc[j][2] + bb[2], 0.f), fmaxf(acc[j][3] + bb[3], 0.f));
            }
        }
        xbar(a.flags, g, rank, ngrp, tok++);

        // ==== P4: GRU for j in [g*128,(g+1)*128), all rows. A staged from
        //     LOCAL pzloc; gh/hf local; h_new -> hf (local) + hb (agent). ====
        for (int r0 = rank; r0 < 32; r0 += ngrp) {
            int mt = r0 & 15, jh = r0 >> 4;
            __syncthreads();
            {
                const __bf16* src = pzloc + (size_t)(mt * 16) * HH + tid * 4;
                u64 tmp[16];
                #pragma unroll
                for (int e = 0; e < 16; e++) tmp[e] = *(const u64*)(src + (size_t)e * HH);
                #pragma unroll
                for (int e = 0; e < 16; e++) *(u64*)(&Alds[e][tid * 4]) = tmp[e];
            }
            __syncthreads();
            int jtg = g * 8 + jh * 4 + v;
            const __bf16* bp0 = a.WIH + (size_t)(jtg * 16 + rr) * HH + ko;
            const __bf16* bp1g = bp0 + (size_t)1024 * HH;
            const __bf16* bp2g = bp0 + (size_t)2048 * HH;
            f32x4 acc[3] = {};
            const __bf16* arow = &Alds[rr][ko];
            #pragma unroll 4
            for (int k = 0; k < HH; k += 32) {
                bf16x8 af = *(const bf16x8*)(arow + k);
                acc[0] = MFMA(*(const bf16x8*)(bp0 + k), af, acc[0], 0, 0, 0);
                acc[1] = MFMA(*(const bf16x8*)(bp1g + k), af, acc[1], 0, 0, 0);
                acc[2] = MFMA(*(const bf16x8*)(bp2g + k), af, acc[2], 0, 0, 0);
            }
            int m = mt * 16 + col;
            int j = jtg * 16 + rq;
            int xb = a.x[m * SS + t];
            const float* gpb = a.gipx + (size_t)xb * 3072;
            f32x4 gp0 = *(const f32x4*)(gpb + j);
            f32x4 gp1 = *(const f32x4*)(gpb + 1024 + j);
            f32x4 gp2 = *(const f32x4*)(gpb + 2048 + j);
            f32x4 br = *(const f32x4*)(a.bih + j);
            f32x4 bz4 = *(const f32x4*)(a.bih + 1024 + j);
            f32x4 bn4 = *(const f32x4*)(a.bih + 2048 + j);
            f32x4 cr = *(const f32x4*)(a.bhh + j);
            f32x4 cz = *(const f32x4*)(a.bhh + 1024 + j);
            f32x4 cn = *(const f32x4*)(a.bhh + 2048 + j);
            const float* ghrow = a.gh + (size_t)m * 3072;
            f32x4 gh0 = *(const f32x4*)(ghrow + j);
            f32x4 gh1 = *(const f32x4*)(ghrow + 1024 + j);
            f32x4 gh2 = *(const f32x4*)(ghrow + 2048 + j);
            f32x4 hcur = *(const f32x4*)(hf[cur] + (size_t)m * HH + j);
            float hv[4];
            #pragma unroll
            for (int i = 0; i < 4; i++) {
                float gir = acc[0][i] + gp0[i] + br[i];
                float giz = acc[1][i] + gp1[i] + bz4[i];
                float gin = acc[2][i] + gp2[i] + bn4[i];
                float ghr = gh0[i] + cr[i];
                float ghz = gh1[i] + cz[i];
                float ghn = gh2[i] + cn[i];
                float rg = sigmoid_(gir + ghr);
                float zg = sigmoid_(giz + ghz);
                float nn = tanhf(gin + rg * ghn);
                hv[i] = (1.f - zg) * nn + zg * hcur[i];
            }
            f32x4 hw = {hv[0], hv[1], hv[2], hv[3]};
            *(f32x4*)(hf[nxt] + (size_t)m * HH + j) = hw;              // local
            st8a(&hb[nxt][(size_t)m * HH + j], pack4bf(hv[0], hv[1], hv[2], hv[3]));
        }
        gbarG(a.bar, gp++, wg, g);
    }

    // ---- tail (final h in hb[0]; batch-partitioned, XCD-local) ----
    // T1: tailhid = relu(h @ pri_w1^T + pb1), K=1024
    for (int r = rank; r < 32; r += ngrp) {
        int mt = v >> 1, nt = r * 2 + (v & 1);
        f32x4 acc[1][1] = {};
        wgemm<1, 1>(hb[0] + (size_t)(base_m + mt * 16) * HH, HH, 0,
                    a.WA + (size_t)(1024 + nt * 16) * HH, HH, 0, HH, acc);
        int n = nt * 16 + col;
        float b = a.pb1[n];
        #pragma unroll
        for (int i = 0; i < 4; i++) {
            int m = base_m + mt * 16 + rq + i;
            a.tailhid[m * HH + n] = (__bf16)fmaxf(acc[0][0][i] + b, 0.f);
        }
    }
    xbar(a.flags, g, rank, ngrp, tok++);
    // T2: pri logits -> z sample (eps[S])
    if (v == 0) {
        for (int r = rank; r < 32; r += ngrp) {
            int mtl = r >> 4, zt = r & 15;
            f32x4 apv[1][1] = {};
            wgemm<1, 1>(a.tailhid + (size_t)(base_m + mtl * 16) * HH, HH, 0,
                        a.W2 + (size_t)(256 + zt * 16) * HH, HH, 0, HH, apv);
            int z = zt * 16 + col;
            float bp = a.pb2[z];
            const float* epst = a.eps + (size_t)SS * BB * ZZ;
            #pragma unroll
            for (int i = 0; i < 4; i++) {
                int m = base_m + mtl * 16 + rq + i;
                float pri = apv[0][0][i] + bp;
                float ps = softplus_(pri);
                a.zbuf[m * ZZ + z] = (__bf16)(epst[m * ZZ + z] * ps + pri);
            }
        }
    }
    xbar(a.flags, g, rank, ngrp, tok++);
    // T3: pz, K=256
    for (int r = rank; r < 32; r += ngrp) {
        int mt = v >> 1, nt = r * 2 + (v & 1);
        f32x4 acc[1][1] = {};
        wgemm<1, 1>(a.zbuf + (size_t)(base_m + mt * 16) * ZZ, ZZ, 0,
                    a.WPZ + (size_t)(nt * 16) * ZZ, ZZ, 0, ZZ, acc);
        int n = nt * 16 + col;
        float b = a.pzb[n];
        #pragma unroll
        for (int i = 0; i < 4; i++) {
            int m = base_m + mt * 16 + rq + i;
            a.pzbuf[m * HH + n] = (__bf16)fmaxf(acc[0][0][i] + b, 0.f);
        }
    }
    xbar(a.flags, g, rank, ngrp, tok++);
    // T4: dec = relu([pz|h] @ dec_w^T + b), K=2048 in two halves
    for (int r = rank; r < 32; r += ngrp) {
        int mt = v >> 1, nt = r * 2 + (v & 1);
        f32x4 acc[1][1] = {};
        wgemm<1, 1>(a.pzbuf + (size_t)(base_m + mt * 16) * HH, HH, 0,
                    a.WDEC + (size_t)(nt * 16) * 2048, 2048, 0, HH, acc);
        wgemm<1, 1>(hb[0] + (size_t)(base_m + mt * 16) * HH, HH, 0,
                    a.WDEC + (size_t)(nt * 16) * 2048 + 1024, 2048, 0, HH, acc);
        int n = nt * 16 + col;
        float b = a.decb[n];
        #pragma unroll
        for (int i = 0; i < 4; i++) {
            int m = base_m + mt * 16 + rq + i;
            a.decbuf[m * HH + n] = (__bf16)fmaxf(acc[0][0][i] + b, 0.f);
        }
    }
    xbar(a.flags, g, rank, ngrp, tok++);
    // T5: pred = dec @ act_w^T + act_b (only slices 0..7)
    if (v == 0) {
        for (int r = rank; r < 32; r += ngrp) {
            if (r >= 8) continue;
            int mt = r >> 2, nt = r & 3;
            f32x4 acc[1][1] = {};
            wgemm<1, 1>(a.decbuf + (size_t)(base_m + mt * 16) * HH, HH, 0,
                        a.WACT + (size_t)(nt * 16) * HH, HH, 0, HH, acc);
            int n = nt * 16 + col;
            float b = a.actb[n];
            #pragma unroll
            for (int i = 0; i < 4; i++) {
                int m = base_m + mt * 16 + rq + i;
                a.out[m * AA + n] = acc[0][0][i] + b;
            }
        }
    }

    // ---- kld reduce: wave -> WG -> device atomic ----
    {
        float s = kl;
        #pragma unroll
        for (int off = 1; off < 64; off <<= 1) s += __shfl_xor(s, off);
        if (lane == 0) sh_kl[v] = s;
        __syncthreads();
        if (tid == 0) {
            float ws = sh_kl[0] + sh_kl[1] + sh_kl[2] + sh_kl[3];
            atomicAdd(a.kldacc, ws);
        }
    }
    gbarG(a.bar, gp++, wg, g);
    if (wg == 0 && tid == 0) {
        float s = __hip_atomic_load(a.kldacc, __ATOMIC_ACQUIRE, __HIP_MEMORY_SCOPE_AGENT);
        a.out[BB * AA] = 0.5f * s;
    }
}

extern "C" void kernel_launch(void* const* d_in, const int* in_sizes, int n_in,
                              void* d_out, int out_size, void* d_ws, size_t ws_size,
                              hipStream_t stream) {
    const int*   x       = (const int*)d_in[0];
    const float* h0      = (const float*)d_in[1];
    const float* eps     = (const float*)d_in[2];
    const float* phi_x_w = (const float*)d_in[3];
    const float* phi_x_b = (const float*)d_in[4];
    const float* enc_w1  = (const float*)d_in[5];
    const float* enc_b1  = (const float*)d_in[6];
    const float* enc_w2  = (const float*)d_in[7];
    const float* enc_b2  = (const float*)d_in[8];
    const float* pri_w1  = (const float*)d_in[9];
    const float* pri_b1  = (const float*)d_in[10];
    const float* pri_w2  = (const float*)d_in[11];
    const float* pri_b2  = (const float*)d_in[12];
    const float* phi_z_w = (const float*)d_in[13];
    const float* phi_z_b = (const float*)d_in[14];
    const float* dec_w   = (const float*)d_in[15];
    const float* dec_b   = (const float*)d_in[16];
    const float* act_w   = (const float*)d_in[17];
    const float* act_b   = (const float*)d_in[18];
    const float* gru_wih = (const float*)d_in[19];
    const float* gru_whh = (const float*)d_in[20];
    const float* gru_bih = (const float*)d_in[21];
    const float* gru_bhh = (const float*)d_in[22];

    char* p = (char*)d_ws;
    auto alloc = [&](size_t bytes) { char* r = p; p += (bytes + 255) & ~(size_t)255; return r; };

    __bf16* WA    = (__bf16*)alloc(2048 * 1024 * 2);
    __bf16* W2    = (__bf16*)alloc(512 * 1024 * 2);
    __bf16* WPZ   = (__bf16*)alloc(1024 * 256 * 2);
    __bf16* WIH   = (__bf16*)alloc(3072 * 1024 * 2);
    __bf16* WHH   = (__bf16*)alloc(3072 * 1024 * 2);
    __bf16* WDEC  = (__bf16*)alloc(1024 * 2048 * 2);
    __bf16* WACT  = (__bf16*)alloc(64 * 1024 * 2);
    float*  px    = (float*)alloc(64 * 1024 * 4);
    float*  encpx = (float*)alloc(64 * 1024 * 4);
    float*  gipx  = (float*)alloc(64 * 3072 * 4);
    float*  hf0   = (float*)alloc(BB * HH * 4);
    float*  hf1   = (float*)alloc(BB * HH * 4);
    __bf16* hb0   = (__bf16*)alloc(BB * HH * 2);
    __bf16* hb1   = (__bf16*)alloc(BB * HH * 2);
    __bf16* hidcat = (__bf16*)alloc(BB * 2048 * 2);
    __bf16* zbuf   = (__bf16*)alloc(BB * ZZ * 2);
    __bf16* pzbuf  = (__bf16*)alloc(BB * HH * 2);
    __bf16* tailhid = (__bf16*)alloc(BB * HH * 2);
    __bf16* decbuf  = (__bf16*)alloc(BB * HH * 2);
    __bf16* zloc8  = (__bf16*)alloc((size_t)8 * BB * ZZ * 2);
    __bf16* pzloc8 = (__bf16*)alloc((size_t)8 * BB * HH * 2);
    float*  gh     = (float*)alloc(BB * 3072 * 4);
    unsigned* bar  = (unsigned*)alloc(4096 * 4);
    unsigned* flags = (unsigned*)alloc(2048 * 4);
    unsigned* cnt  = (unsigned*)alloc(64 * 4);
    float*  kldacc = (float*)alloc(256);

    auto pack = [&](const float* src, int src_ld, int off, __bf16* dst, int rows, int cols) {
        int total = rows * cols;
        k_pack<<<(total + 255) / 256, 256, 0, stream>>>(src, src_ld, off, dst, cols, total);
    };

    k_zeroctl<<<1, 256, 0, stream>>>(bar, flags, cnt, kldacc);
    pack(enc_w1, 2048, 1024, WA, 1024, 1024);
    pack(pri_w1, 1024, 0, WA + 1024 * 1024, 1024, 1024);
    pack(enc_w2, 1024, 0, W2, 256, 1024);
    pack(pri_w2, 1024, 0, W2 + 256 * 1024, 256, 1024);
    pack(phi_z_w, 256, 0, WPZ, 1024, 256);
    pack(gru_wih, 2048, 1024, WIH, 3072, 1024);
    pack(gru_whh, 1024, 0, WHH, 3072, 1024);
    pack(dec_w, 2048, 0, WDEC, 1024, 2048);
    pack(act_w, 1024, 0, WACT, 64, 1024);
    pack(h0, 1024, 0, hb0, 256, 1024);
    k_copyf<<<(BB * HH + 255) / 256, 256, 0, stream>>>(h0, hf0, BB * HH);
    k_px<<<(64 * 1024) / 256, 256, 0, stream>>>(phi_x_w, phi_x_b, px);
    k_tables<<<1024, 256, 0, stream>>>(enc_w1, gru_wih, px, encpx, gipx);

    PArgs pa;
    pa.x = x; pa.eps = eps;
    pa.WA = WA; pa.W2 = W2; pa.WPZ = WPZ; pa.WIH = WIH; pa.WHH = WHH;
    pa.WDEC = WDEC; pa.WACT = WACT;
    pa.encpx = encpx; pa.gipx = gipx;
    pa.eb1 = enc_b1; pa.pb1 = pri_b1; pa.eb2 = enc_b2; pa.pb2 = pri_b2;
    pa.pzb = phi_z_b; pa.decb = dec_b; pa.actb = act_b;
    pa.bih = gru_bih; pa.bhh = gru_bhh;
    pa.hf0 = hf0; pa.hf1 = hf1; pa.hb0 = hb0; pa.hb1 = hb1;
    pa.hidcat = hidcat; pa.zbuf = zbuf; pa.pzbuf = pzbuf;
    pa.tailhid = tailhid; pa.decbuf = decbuf;
    pa.zloc8 = zloc8; pa.pzloc8 = pzloc8;
    pa.gh = gh; pa.kldacc = kldacc;
    pa.bar = bar; pa.flags = flags; pa.cnt = cnt;
    pa.out = (float*)d_out;

    k_persist<<<dim3(NWG), dim3(256), 0, stream>>>(pa);
}

// Round 5
// 29057.715 us; speedup vs baseline: 1.4196x; 1.4196x over previous
//
#include <hip/hip_runtime.h>

// CVRAE forward, XCD-local persistent version — 8-wave WGs.
// B=256, S=512, A=64, H=1024, Z=256.
// Structure = R2 (best, 27.86ms): NWG=256 (1 WG/CU), batch split 32 rows/XCD,
// all dataflow XCD-local, 4 per-XCD flag barriers/step.
// Round-5 change ONLY: 512-thread WGs (8 waves -> 2 waves/SIMD) to double
// memory-level parallelism of the LLC->L2 weight streams. Same barrier
// topology (32 WGs/XCD), same per-WG work. P1: (mt,nh,kh) 8-way split, MT=1,
// K=512/wave; P4: (mt,jh,kh) 8-way; both use i-half finalization (each K-half
// wave finalizes 2 of its 4 acc rows; partner partials via LDS, stride-17
// padded). P2: K split 8x128. P3 + tail run on waves 0-3 (tiny phases).

typedef float f32x4 __attribute__((ext_vector_type(4)));
typedef __bf16 bf16x8 __attribute__((ext_vector_type(8)));

#define BB 256
#define SS 512
#define HH 1024
#define ZZ 256
#define AA 64
#define NWG 256
#define MFMA __builtin_amdgcn_mfma_f32_16x16x32_bf16

__device__ __forceinline__ float softplus_(float x) {
    return (x > 15.f) ? x : log1pf(expf(x));
}
__device__ __forceinline__ float sigmoid_(float x) {
    return 1.f / (1.f + expf(-x));
}

// ---------------- global (agent) barrier — used ONLY twice ----------------
__device__ __forceinline__ void gbar(unsigned* bar, unsigned p, int wg) {
    __syncthreads();
    if (threadIdx.x == 0) {
        unsigned s = p & 7u;
        unsigned exp = (p >> 3) + 1u;
        unsigned* leaf = bar + (s * 8 + (wg >> 5)) * 16;
        unsigned* root = bar + (64 + s) * 16;
        unsigned* flag = bar + (72 + s) * 16;
        unsigned old = __hip_atomic_fetch_add(leaf, 1u, __ATOMIC_ACQ_REL, __HIP_MEMORY_SCOPE_AGENT);
        if (old == 32u * exp - 1u) {
            unsigned old2 = __hip_atomic_fetch_add(root, 1u, __ATOMIC_ACQ_REL, __HIP_MEMORY_SCOPE_AGENT);
            if (old2 == 8u * exp - 1u) {
                __hip_atomic_store(flag, exp, __ATOMIC_RELEASE, __HIP_MEMORY_SCOPE_AGENT);
            }
        }
        while (__hip_atomic_load(flag, __ATOMIC_ACQUIRE, __HIP_MEMORY_SCOPE_AGENT) < exp) {
            __builtin_amdgcn_s_sleep(2);
        }
    }
    __syncthreads();
}

// ---------------- per-XCD barrier ----------------
__device__ __forceinline__ void xbar(unsigned* flags, int g, int rank, int ngrp,
                                     unsigned tok) {
    __syncthreads();   // all waves' stores drained to L2, exec sync
    if (threadIdx.x == 0)
        __hip_atomic_store(flags + g * 256 + rank, tok, __ATOMIC_RELAXED,
                           __HIP_MEMORY_SCOPE_AGENT);
    unsigned l = threadIdx.x & 63;
    unsigned* base = flags + g * 256;
    for (;;) {
        bool ok = true;
        for (int i = (int)l; i < ngrp; i += 64)
            ok &= (__hip_atomic_load(base + i, __ATOMIC_RELAXED,
                                     __HIP_MEMORY_SCOPE_AGENT) >= tok);
        if (__all(ok)) break;
        __builtin_amdgcn_s_sleep(2);
    }
    asm volatile("buffer_inv sc0" ::: "memory");   // invalidate per-CU L1 only
}

// ---------------- wave GEMM helper (tail) ----------------
template<int MT, int NT>
__device__ __forceinline__ void wgemm(const __bf16* __restrict__ A, int lda, int mstride,
                                      const __bf16* __restrict__ B, int ldb, int nstride,
                                      int K, f32x4 (&acc)[MT][NT]) {
    int lane = threadIdx.x & 63;
    int rr = lane & 15;
    int ko = (lane >> 4) * 8;
    const __bf16* ap = A + rr * lda + ko;
    const __bf16* bp = B + rr * ldb + ko;
    #pragma unroll 2
    for (int k = 0; k < K; k += 32) {
        bf16x8 af[MT], bfr[NT];
        #pragma unroll
        for (int mt = 0; mt < MT; mt++) af[mt] = *(const bf16x8*)(ap + mt * mstride + k);
        #pragma unroll
        for (int nt = 0; nt < NT; nt++) bfr[nt] = *(const bf16x8*)(bp + nt * nstride + k);
        #pragma unroll
        for (int mt = 0; mt < MT; mt++)
            #pragma unroll
            for (int nt = 0; nt < NT; nt++)
                acc[mt][nt] = MFMA(af[mt], bfr[nt], acc[mt][nt], 0, 0, 0);
    }
}

// ---------------- prep kernels ----------------

__global__ void k_zeroctl(unsigned* bar, unsigned* flags, unsigned* cnt, float* kldacc) {
    for (int i = threadIdx.x; i < 1280; i += 256) bar[i] = 0u;
    for (int i = threadIdx.x; i < 2048; i += 256) flags[i] = 0u;
    if (threadIdx.x < 8) cnt[threadIdx.x] = 0u;
    if (threadIdx.x == 0) *kldacc = 0.f;
}

__global__ void k_pack(const float* __restrict__ src, int src_ld, int col_off,
                       __bf16* __restrict__ dst, int cols, int total) {
    int i = blockIdx.x * 256 + threadIdx.x;
    if (i >= total) return;
    int r = i / cols, c = i - r * cols;
    dst[i] = (__bf16)src[r * src_ld + col_off + c];
}

__global__ void k_copyf(const float* __restrict__ s, float* __restrict__ d, int n) {
    int i = blockIdx.x * 256 + threadIdx.x;
    if (i < n) d[i] = s[i];
}

__global__ void k_px(const float* __restrict__ phi_x_w, const float* __restrict__ phi_x_b,
                     float* __restrict__ px) {
    int i = blockIdx.x * 256 + threadIdx.x;  // 64*1024
    int a = i >> 10, hh = i & 1023;
    px[i] = fmaxf(phi_x_w[hh * AA + a] + phi_x_b[hh], 0.f);
}

__global__ __launch_bounds__(256) void k_tables(const float* __restrict__ enc_w1,
                                                const float* __restrict__ wih,
                                                const float* __restrict__ px,
                                                float* __restrict__ encpx,
                                                float* __restrict__ gipx) {
    __shared__ float spx[64][65];
    int tid = threadIdx.x;
    int cg = blockIdx.x * 4 + (tid >> 6);
    int a = tid & 63;
    const float* wrow = (cg < 1024) ? (enc_w1 + cg * 2048) : (wih + (cg - 1024) * 2048);
    float sum = 0.f;
    for (int k0 = 0; k0 < 1024; k0 += 64) {
        __syncthreads();
        for (int e = tid; e < 4096; e += 256)
            spx[e >> 6][e & 63] = px[((e >> 6) << 10) + k0 + (e & 63)];
        __syncthreads();
        #pragma unroll 8
        for (int kk = 0; kk < 64; kk++) sum += wrow[k0 + kk] * spx[a][kk];
    }
    if (cg < 1024) encpx[a * 1024 + cg] = sum;
    else gipx[a * 3072 + (cg - 1024)] = sum;
}

// ---------------- persistent kernel ----------------

struct PArgs {
    const int* x; const float* eps;
    const __bf16 *WA, *W2, *WPZ, *WIH, *WHH, *WDEC, *WACT;
    const float *encpx, *gipx;
    const float *eb1, *pb1, *eb2, *pb2, *pzb, *decb, *actb, *bih, *bhh;
    float *hf0, *hf1; __bf16 *hb0, *hb1;
    __bf16 *hidcat, *zbuf, *pzbuf, *tailhid, *decbuf;
    float *gh; float *kldacc; unsigned *bar, *flags, *cnt;
    float* out;
};

__global__ __launch_bounds__(512, 1) void k_persist(PArgs a) {
    int wg = blockIdx.x;
    int tid = threadIdx.x;
    int v = tid >> 6;                // wave in WG, 0..7
    int lane = tid & 63;
    int rr = lane & 15;              // fragment row
    int ko = (lane >> 4) * 8;        // fragment k-offset
    int col = lane & 15, rq = (lane >> 4) * 4;
    float kl = 0.f;
    float* hf[2] = {a.hf0, a.hf1};
    __bf16* hb[2] = {a.hb0, a.hb1};

    __shared__ float ldsC[5440];         // P1: 20 tiles *272, P4: 12 tiles *272 (stride 17)
    __shared__ float lds2[8][2][272];    // P2 K-split partials (stride-17 rows)
    __shared__ int sh_g, sh_rank, sh_ngrp;
    __shared__ float sh_kl[8];

    // ---- XCD registration (mapping-robust grouping) ----
    if (tid == 0) {
        unsigned xcc = __builtin_amdgcn_s_getreg((31 << 11) | (0 << 6) | 20) & 7u;
        sh_g = (int)xcc;
        sh_rank = (int)atomicAdd(a.cnt + xcc, 1u);
    }
    __syncthreads();
    int g = sh_g, rank = sh_rank;
    gbar(a.bar, 0, wg);                 // counts final + cache sync
    if (tid == 0)
        sh_ngrp = (int)__hip_atomic_load(a.cnt + g, __ATOMIC_RELAXED,
                                         __HIP_MEMORY_SCOPE_AGENT);
    __syncthreads();
    int ngrp = sh_ngrp;
    int base_m = g * 32;                // this XCD's 32 batch rows

    unsigned tok = 1;

    for (int t = 0; t < SS; t++) {
        int cur = t & 1, nxt = cur ^ 1;

        // ---- P1: hidcat (cols 0..2047) + gh (cols 2048..5119), K=1024 ----
        // Item r: 10 n-tiles x 2 m-tiles. 8 waves: (mt=v&1, nh=(v>>1)&1 -> 5
        // n-tiles, kh=v>>2 -> K-half). Each wave finalizes i-half = kh*2..+1
        // of its 4 acc rows; partner's i-half partials cross via LDS.
        for (int r = rank; r < 32; r += ngrp) {
            int mt = v & 1, nh = (v >> 1) & 1, kh = v >> 2;
            int nt0 = r * 10 + nh * 5;
            const __bf16* ap = hb[cur] + (size_t)(base_m + mt * 16 + rr) * HH + kh * 512 + ko;
            const __bf16* bp[5];
            #pragma unroll
            for (int j = 0; j < 5; j++) {
                int n = (nt0 + j) * 16 + rr;
                bp[j] = ((n < 2048) ? (a.WA + (size_t)n * HH)
                                    : (a.WHH + (size_t)(n - 2048) * HH)) + kh * 512 + ko;
            }
            f32x4 acc[5] = {};
            #pragma unroll 4
            for (int k = 0; k < 512; k += 32) {
                bf16x8 af = *(const bf16x8*)(ap + k);
                #pragma unroll
                for (int j = 0; j < 5; j++)
                    acc[j] = MFMA(af, *(const bf16x8*)(bp[j] + k), acc[j], 0, 0, 0);
            }
            // write partner's i-half partials
            int iw = (kh ^ 1) * 2;
            #pragma unroll
            for (int j = 0; j < 5; j++)
                #pragma unroll
                for (int d = 0; d < 2; d++)
                    ldsC[((mt * 2 + nh) * 5 + j) * 272 + (rq + iw + d) * 17 + col] = acc[j][iw + d];
            __syncthreads();
            // finalize own i-half
            int ir = kh * 2;
            int xb[2];
            #pragma unroll
            for (int d = 0; d < 2; d++)
                xb[d] = a.x[(base_m + mt * 16 + rq + ir + d) * SS + t];
            #pragma unroll
            for (int j = 0; j < 5; j++) {
                int c0 = (nt0 + j) * 16 + col;
                float fin[2];
                #pragma unroll
                for (int d = 0; d < 2; d++)
                    fin[d] = acc[j][ir + d] +
                             ldsC[((mt * 2 + nh) * 5 + j) * 272 + (rq + ir + d) * 17 + col];
                if (c0 < 1024) {
                    float bias = a.eb1[c0];
                    #pragma unroll
                    for (int d = 0; d < 2; d++) {
                        int m = base_m + mt * 16 + rq + ir + d;
                        float val = fin[d] + bias + a.encpx[xb[d] * 1024 + c0];
                        a.hidcat[m * 2048 + c0] = (__bf16)fmaxf(val, 0.f);
                    }
                } else if (c0 < 2048) {
                    float bias = a.pb1[c0 - 1024];
                    #pragma unroll
                    for (int d = 0; d < 2; d++) {
                        int m = base_m + mt * 16 + rq + ir + d;
                        a.hidcat[m * 2048 + c0] = (__bf16)fmaxf(fin[d] + bias, 0.f);
                    }
                } else {
                    int gc = c0 - 2048;
                    #pragma unroll
                    for (int d = 0; d < 2; d++) {
                        int m = base_m + mt * 16 + rq + ir + d;
                        a.gh[m * 3072 + gc] = fin[d];
                    }
                }
            }
            __syncthreads();   // protect ldsC across r-iterations
        }
        xbar(a.flags, g, rank, ngrp, tok++);

        // ---- P2: enc/pri logits (K split over 8 waves x 128), kld, z ----
        for (int r = rank; r < 32; r += ngrp) {
            int mtl = r >> 4, zsl = r & 15;
            const __bf16* ae_p = a.hidcat + (size_t)(base_m + mtl * 16 + rr) * 2048 + v * 128 + ko;
            const __bf16* ap_p = ae_p + 1024;
            const __bf16* be_p = a.W2 + (size_t)(zsl * 16 + rr) * HH + v * 128 + ko;
            const __bf16* bp_p = a.W2 + (size_t)(256 + zsl * 16 + rr) * HH + v * 128 + ko;
            f32x4 ae = {0.f,0.f,0.f,0.f}, av = {0.f,0.f,0.f,0.f};
            #pragma unroll
            for (int k = 0; k < 128; k += 32) {
                ae = MFMA(*(const bf16x8*)(ae_p + k), *(const bf16x8*)(be_p + k), ae, 0, 0, 0);
                av = MFMA(*(const bf16x8*)(ap_p + k), *(const bf16x8*)(bp_p + k), av, 0, 0, 0);
            }
            #pragma unroll
            for (int i = 0; i < 4; i++) {
                int idx = (rq + i) * 17 + col;
                lds2[v][0][idx] = ae[i];
                lds2[v][1][idx] = av[i];
            }
            __syncthreads();
            if (tid < 256) {
                int idx = (tid >> 4) * 17 + (tid & 15);
                float e = 0.f, pv = 0.f;
                #pragma unroll
                for (int w8 = 0; w8 < 8; w8++) {
                    e += lds2[w8][0][idx];
                    pv += lds2[w8][1][idx];
                }
                int m = base_m + mtl * 16 + (tid >> 4);
                int z = zsl * 16 + (tid & 15);
                float enc = e + a.eb2[z];
                float pri = pv + a.pb2[z];
                float es = softplus_(enc), ps = softplus_(pri);
                float d = enc - pri;
                kl += 2.f * (logf(ps) - logf(es)) + (es * es + d * d) / (ps * ps) - 1.f;
                const float* epst = a.eps + (size_t)t * BB * ZZ;
                a.zbuf[m * ZZ + z] = (__bf16)(epst[m * ZZ + z] * es + enc);
            }
            __syncthreads();
        }
        xbar(a.flags, g, rank, ngrp, tok++);

        // ---- P3: pz = relu(z @ phi_z_w^T + b), K=256 (waves 0-3; tiny) ----
        if (v < 4) {
            for (int r = rank; r < 32; r += ngrp) {
                int mt = v >> 1;
                int nt = r * 2 + (v & 1);
                const __bf16* ap = a.zbuf + (size_t)(base_m + mt * 16 + rr) * ZZ + ko;
                const __bf16* bp = a.WPZ + (size_t)(nt * 16 + rr) * ZZ + ko;
                f32x4 acc = {0.f,0.f,0.f,0.f};
                #pragma unroll
                for (int k = 0; k < ZZ; k += 32)
                    acc = MFMA(*(const bf16x8*)(ap + k), *(const bf16x8*)(bp + k), acc, 0, 0, 0);
                int n = nt * 16 + col;
                float b = a.pzb[n];
                #pragma unroll
                for (int i = 0; i < 4; i++) {
                    int m = base_m + mt * 16 + rq + i;
                    a.pzbuf[m * HH + n] = (__bf16)fmaxf(acc[i] + b, 0.f);
                }
            }
        }
        xbar(a.flags, g, rank, ngrp, tok++);

        // ---- P4: gi (3 gates) + gate math + h_new, K=1024 ----
        // Item r: 2 j-tiles x 2 m-tiles. 8 waves: (mt=v&1, jh=(v>>1)&1,
        // kh=v>>2 -> K-half). i-half finalization as in P1.
        for (int r = rank; r < 32; r += ngrp) {
            int mt = v & 1, jh = (v >> 1) & 1, kh = v >> 2;
            int jt = r * 2 + jh;
            const __bf16* ap = a.pzbuf + (size_t)(base_m + mt * 16 + rr) * HH + kh * 512 + ko;
            const __bf16* bp0 = a.WIH + (size_t)(jt * 16 + rr) * HH + kh * 512 + ko;
            const __bf16* bp1g = bp0 + (size_t)1024 * HH;
            const __bf16* bp2g = bp0 + (size_t)2048 * HH;
            f32x4 acc[3] = {};
            #pragma unroll 4
            for (int k = 0; k < 512; k += 32) {
                bf16x8 af = *(const bf16x8*)(ap + k);
                acc[0] = MFMA(af, *(const bf16x8*)(bp0 + k), acc[0], 0, 0, 0);
                acc[1] = MFMA(af, *(const bf16x8*)(bp1g + k), acc[1], 0, 0, 0);
                acc[2] = MFMA(af, *(const bf16x8*)(bp2g + k), acc[2], 0, 0, 0);
            }
            int iw = (kh ^ 1) * 2;
            #pragma unroll
            for (int g3 = 0; g3 < 3; g3++)
                #pragma unroll
                for (int d = 0; d < 2; d++)
                    ldsC[((mt * 2 + jh) * 3 + g3) * 272 + (rq + iw + d) * 17 + col] = acc[g3][iw + d];
            __syncthreads();
            int ir = kh * 2;
            int j = jt * 16 + col;
            float br = a.bih[j], bz2 = a.bih[1024 + j], bn = a.bih[2048 + j];
            float cr = a.bhh[j], cz = a.bhh[1024 + j], cn = a.bhh[2048 + j];
            #pragma unroll
            for (int d = 0; d < 2; d++) {
                float fin[3];
                #pragma unroll
                for (int g3 = 0; g3 < 3; g3++)
                    fin[g3] = acc[g3][ir + d] +
                              ldsC[((mt * 2 + jh) * 3 + g3) * 272 + (rq + ir + d) * 17 + col];
                int m = base_m + mt * 16 + rq + ir + d;
                int xb = a.x[m * SS + t];
                const float* gp = a.gipx + (size_t)xb * 3072;
                float gir = fin[0] + gp[j] + br;
                float giz = fin[1] + gp[1024 + j] + bz2;
                float gin = fin[2] + gp[2048 + j] + bn;
                float ghr = a.gh[m * 3072 + j] + cr;
                float ghz = a.gh[m * 3072 + 1024 + j] + cz;
                float ghn = a.gh[m * 3072 + 2048 + j] + cn;
                float rg = sigmoid_(gir + ghr);
                float zg = sigmoid_(giz + ghz);
                float nn = tanhf(gin + rg * ghn);
                float hv = (1.f - zg) * nn + zg * hf[cur][m * HH + j];
                hf[nxt][m * HH + j] = hv;
                hb[nxt][m * HH + j] = (__bf16)hv;
            }
            __syncthreads();   // protect ldsC across r-iterations
        }
        xbar(a.flags, g, rank, ngrp, tok++);
    }

    // ---- tail (final h in buffer 0, per-XCD rows; waves 0-3) ----
    // T1: tailhid = relu(h @ pri_w1^T + pb1), K=1024
    if (v < 4) {
        for (int r = rank; r < 32; r += ngrp) {
            int mt = v >> 1, nt = r * 2 + (v & 1);
            f32x4 acc[1][1] = {};
            wgemm<1, 1>(hb[0] + (size_t)(base_m + mt * 16) * HH, HH, 0,
                        a.WA + (size_t)(1024 + nt * 16) * HH, HH, 0, HH, acc);
            int n = nt * 16 + col;
            float b = a.pb1[n];
            #pragma unroll
            for (int i = 0; i < 4; i++) {
                int m = base_m + mt * 16 + rq + i;
                a.tailhid[m * HH + n] = (__bf16)fmaxf(acc[0][0][i] + b, 0.f);
            }
        }
    }
    xbar(a.flags, g, rank, ngrp, tok++);
    // T2: pri logits -> z sample (eps[S])
    if (v == 0) {
        for (int r = rank; r < 32; r += ngrp) {
            int mtl = r >> 4, zt = r & 15;
            f32x4 apv[1][1] = {};
            wgemm<1, 1>(a.tailhid + (size_t)(base_m + mtl * 16) * HH, HH, 0,
                        a.W2 + (size_t)(256 + zt * 16) * HH, HH, 0, HH, apv);
            int z = zt * 16 + col;
            float bp = a.pb2[z];
            const float* epst = a.eps + (size_t)SS * BB * ZZ;
            #pragma unroll
            for (int i = 0; i < 4; i++) {
                int m = base_m + mtl * 16 + rq + i;
                float pri = apv[0][0][i] + bp;
                float ps = softplus_(pri);
                a.zbuf[m * ZZ + z] = (__bf16)(epst[m * ZZ + z] * ps + pri);
            }
        }
    }
    xbar(a.flags, g, rank, ngrp, tok++);
    // T3: pz, K=256
    if (v < 4) {
        for (int r = rank; r < 32; r += ngrp) {
            int mt = v >> 1, nt = r * 2 + (v & 1);
            f32x4 acc[1][1] = {};
            wgemm<1, 1>(a.zbuf + (size_t)(base_m + mt * 16) * ZZ, ZZ, 0,
                        a.WPZ + (size_t)(nt * 16) * ZZ, ZZ, 0, ZZ, acc);
            int n = nt * 16 + col;
            float b = a.pzb[n];
            #pragma unroll
            for (int i = 0; i < 4; i++) {
                int m = base_m + mt * 16 + rq + i;
                a.pzbuf[m * HH + n] = (__bf16)fmaxf(acc[0][0][i] + b, 0.f);
            }
        }
    }
    xbar(a.flags, g, rank, ngrp, tok++);
    // T4: dec = relu([pz|h] @ dec_w^T + b), K=2048 in two halves
    if (v < 4) {
        for (int r = rank; r < 32; r += ngrp) {
            int mt = v >> 1, nt = r * 2 + (v & 1);
            f32x4 acc[1][1] = {};
            wgemm<1, 1>(a.pzbuf + (size_t)(base_m + mt * 16) * HH, HH, 0,
                        a.WDEC + (size_t)(nt * 16) * 2048, 2048, 0, HH, acc);
            wgemm<1, 1>(hb[0] + (size_t)(base_m + mt * 16) * HH, HH, 0,
                        a.WDEC + (size_t)(nt * 16) * 2048 + 1024, 2048, 0, HH, acc);
            int n = nt * 16 + col;
            float b = a.decb[n];
            #pragma unroll
            for (int i = 0; i < 4; i++) {
                int m = base_m + mt * 16 + rq + i;
                a.decbuf[m * HH + n] = (__bf16)fmaxf(acc[0][0][i] + b, 0.f);
            }
        }
    }
    xbar(a.flags, g, rank, ngrp, tok++);
    // T5: pred = dec @ act_w^T + act_b (only slices 0..7)
    if (v == 0) {
        for (int r = rank; r < 32; r += ngrp) {
            if (r >= 8) continue;
            int mt = r >> 2, nt = r & 3;
            f32x4 acc[1][1] = {};
            wgemm<1, 1>(a.decbuf + (size_t)(base_m + mt * 16) * HH, HH, 0,
                        a.WACT + (size_t)(nt * 16) * HH, HH, 0, HH, acc);
            int n = nt * 16 + col;
            float b = a.actb[n];
            #pragma unroll
            for (int i = 0; i < 4; i++) {
                int m = base_m + mt * 16 + rq + i;
                a.out[m * AA + n] = acc[0][0][i] + b;
            }
        }
    }

    // ---- kld reduce: wave -> WG -> device atomic ----
    {
        float s = kl;
        #pragma unroll
        for (int off = 1; off < 64; off <<= 1) s += __shfl_xor(s, off);
        if (lane == 0) sh_kl[v] = s;
        __syncthreads();
        if (tid == 0) {
            float ws = 0.f;
            #pragma unroll
            for (int w8 = 0; w8 < 8; w8++) ws += sh_kl[w8];
            atomicAdd(a.kldacc, ws);
        }
    }
    gbar(a.bar, 1, wg);
    if (wg == 0 && tid == 0) {
        float s = __hip_atomic_load(a.kldacc, __ATOMIC_ACQUIRE, __HIP_MEMORY_SCOPE_AGENT);
        a.out[BB * AA] = 0.5f * s;
    }
}

extern "C" void kernel_launch(void* const* d_in, const int* in_sizes, int n_in,
                              void* d_out, int out_size, void* d_ws, size_t ws_size,
                              hipStream_t stream) {
    const int*   x       = (const int*)d_in[0];
    const float* h0      = (const float*)d_in[1];
    const float* eps     = (const float*)d_in[2];
    const float* phi_x_w = (const float*)d_in[3];
    const float* phi_x_b = (const float*)d_in[4];
    const float* enc_w1  = (const float*)d_in[5];
    const float* enc_b1  = (const float*)d_in[6];
    const float* enc_w2  = (const float*)d_in[7];
    const float* enc_b2  = (const float*)d_in[8];
    const float* pri_w1  = (const float*)d_in[9];
    const float* pri_b1  = (const float*)d_in[10];
    const float* pri_w2  = (const float*)d_in[11];
    const float* pri_b2  = (const float*)d_in[12];
    const float* phi_z_w = (const float*)d_in[13];
    const float* phi_z_b = (const float*)d_in[14];
    const float* dec_w   = (const float*)d_in[15];
    const float* dec_b   = (const float*)d_in[16];
    const float* act_w   = (const float*)d_in[17];
    const float* act_b   = (const float*)d_in[18];
    const float* gru_wih = (const float*)d_in[19];
    const float* gru_whh = (const float*)d_in[20];
    const float* gru_bih = (const float*)d_in[21];
    const float* gru_bhh = (const float*)d_in[22];

    char* p = (char*)d_ws;
    auto alloc = [&](size_t bytes) { char* r = p; p += (bytes + 255) & ~(size_t)255; return r; };

    __bf16* WA    = (__bf16*)alloc(2048 * 1024 * 2);
    __bf16* W2    = (__bf16*)alloc(512 * 1024 * 2);
    __bf16* WPZ   = (__bf16*)alloc(1024 * 256 * 2);
    __bf16* WIH   = (__bf16*)alloc(3072 * 1024 * 2);
    __bf16* WHH   = (__bf16*)alloc(3072 * 1024 * 2);
    __bf16* WDEC  = (__bf16*)alloc(1024 * 2048 * 2);
    __bf16* WACT  = (__bf16*)alloc(64 * 1024 * 2);
    float*  px    = (float*)alloc(64 * 1024 * 4);
    float*  encpx = (float*)alloc(64 * 1024 * 4);
    float*  gipx  = (float*)alloc(64 * 3072 * 4);
    float*  hf0   = (float*)alloc(BB * HH * 4);
    float*  hf1   = (float*)alloc(BB * HH * 4);
    __bf16* hb0   = (__bf16*)alloc(BB * HH * 2);
    __bf16* hb1   = (__bf16*)alloc(BB * HH * 2);
    __bf16* hidcat = (__bf16*)alloc(BB * 2048 * 2);
    __bf16* zbuf   = (__bf16*)alloc(BB * ZZ * 2);
    __bf16* pzbuf  = (__bf16*)alloc(BB * HH * 2);
    __bf16* tailhid = (__bf16*)alloc(BB * HH * 2);
    __bf16* decbuf  = (__bf16*)alloc(BB * HH * 2);
    float*  gh     = (float*)alloc(BB * 3072 * 4);
    unsigned* bar  = (unsigned*)alloc(1280 * 4);
    unsigned* flags = (unsigned*)alloc(2048 * 4);
    unsigned* cnt  = (unsigned*)alloc(64 * 4);
    float*  kldacc = (float*)alloc(256);

    auto pack = [&](const float* src, int src_ld, int off, __bf16* dst, int rows, int cols) {
        int total = rows * cols;
        k_pack<<<(total + 255) / 256, 256, 0, stream>>>(src, src_ld, off, dst, cols, total);
    };

    k_zeroctl<<<1, 256, 0, stream>>>(bar, flags, cnt, kldacc);
    pack(enc_w1, 2048, 1024, WA, 1024, 1024);
    pack(pri_w1, 1024, 0, WA + 1024 * 1024, 1024, 1024);
    pack(enc_w2, 1024, 0, W2, 256, 1024);
    pack(pri_w2, 1024, 0, W2 + 256 * 1024, 256, 1024);
    pack(phi_z_w, 256, 0, WPZ, 1024, 256);
    pack(gru_wih, 2048, 1024, WIH, 3072, 1024);
    pack(gru_whh, 1024, 0, WHH, 3072, 1024);
    pack(dec_w, 2048, 0, WDEC, 1024, 2048);
    pack(act_w, 1024, 0, WACT, 64, 1024);
    pack(h0, 1024, 0, hb0, 256, 1024);
    k_copyf<<<(BB * HH + 255) / 256, 256, 0, stream>>>(h0, hf0, BB * HH);
    k_px<<<(64 * 1024) / 256, 256, 0, stream>>>(phi_x_w, phi_x_b, px);
    k_tables<<<1024, 256, 0, stream>>>(enc_w1, gru_wih, px, encpx, gipx);

    PArgs pa;
    pa.x = x; pa.eps = eps;
    pa.WA = WA; pa.W2 = W2; pa.WPZ = WPZ; pa.WIH = WIH; pa.WHH = WHH;
    pa.WDEC = WDEC; pa.WACT = WACT;
    pa.encpx = encpx; pa.gipx = gipx;
    pa.eb1 = enc_b1; pa.pb1 = pri_b1; pa.eb2 = enc_b2; pa.pb2 = pri_b2;
    pa.pzb = phi_z_b; pa.decb = dec_b; pa.actb = act_b;
    pa.bih = gru_bih; pa.bhh = gru_bhh;
    pa.hf0 = hf0; pa.hf1 = hf1; pa.hb0 = hb0; pa.hb1 = hb1;
    pa.hidcat = hidcat; pa.zbuf = zbuf; pa.pzbuf = pzbuf;
    pa.tailhid = tailhid; pa.decbuf = decbuf;
    pa.gh = gh; pa.kldacc = kldacc;
    pa.bar = bar; pa.flags = flags; pa.cnt = cnt;
    pa.out = (float*)d_out;

    k_persist<<<dim3(NWG), dim3(512), 0, stream>>>(pa);
}

// Round 6
// 28308.624 us; speedup vs baseline: 1.4572x; 1.0265x over previous
//
#include <hip/hip_runtime.h>

// CVRAE forward, XCD-local persistent version.
// B=256, S=512, A=64, H=1024, Z=256.
// Base = R2 (best, 27.86ms): NWG=256 (1 WG/CU), 32 WGs/XCD, batch split
// 32 rows/XCD, all dataflow XCD-local, 4 per-XCD flag barriers/step.
// P1/P4: MT=2 + 2-way K-split across wave pairs + LDS combine.
// Round-6 change ONLY: each XCD walks its work items in an order rotated by
// g*4 (item = (r + g*4) & 31). Identical work; but the 8 XCDs no longer
// stream the SAME weight lines in lockstep -> LLC slice requests spread
// ~2.5MB apart instead of hot-spotting one slice. Tests the hypothesis that
// the ~1.5-1.8 TB/s fill ceiling is same-address LLC contention.

typedef float f32x4 __attribute__((ext_vector_type(4)));
typedef __bf16 bf16x8 __attribute__((ext_vector_type(8)));

#define BB 256
#define SS 512
#define HH 1024
#define ZZ 256
#define AA 64
#define NWG 256

__device__ __forceinline__ float softplus_(float x) {
    return (x > 15.f) ? x : log1pf(expf(x));
}
__device__ __forceinline__ float sigmoid_(float x) {
    return 1.f / (1.f + expf(-x));
}

// ---------------- global (agent) barrier — used ONLY twice ----------------
__device__ __forceinline__ void gbar(unsigned* bar, unsigned p, int wg) {
    __syncthreads();
    if (threadIdx.x == 0) {
        unsigned s = p & 7u;
        unsigned exp = (p >> 3) + 1u;
        unsigned* leaf = bar + (s * 8 + (wg >> 5)) * 16;
        unsigned* root = bar + (64 + s) * 16;
        unsigned* flag = bar + (72 + s) * 16;
        unsigned old = __hip_atomic_fetch_add(leaf, 1u, __ATOMIC_ACQ_REL, __HIP_MEMORY_SCOPE_AGENT);
        if (old == 32u * exp - 1u) {
            unsigned old2 = __hip_atomic_fetch_add(root, 1u, __ATOMIC_ACQ_REL, __HIP_MEMORY_SCOPE_AGENT);
            if (old2 == 8u * exp - 1u) {
                __hip_atomic_store(flag, exp, __ATOMIC_RELEASE, __HIP_MEMORY_SCOPE_AGENT);
            }
        }
        while (__hip_atomic_load(flag, __ATOMIC_ACQUIRE, __HIP_MEMORY_SCOPE_AGENT) < exp) {
            __builtin_amdgcn_s_sleep(2);
        }
    }
    __syncthreads();
}

// ---------------- per-XCD barrier ----------------
__device__ __forceinline__ void xbar(unsigned* flags, int g, int rank, int ngrp,
                                     unsigned tok) {
    __syncthreads();   // all waves' stores drained to L2, exec sync
    if (threadIdx.x == 0)
        __hip_atomic_store(flags + g * 256 + rank, tok, __ATOMIC_RELAXED,
                           __HIP_MEMORY_SCOPE_AGENT);
    unsigned l = threadIdx.x & 63;
    unsigned* base = flags + g * 256;
    for (;;) {
        bool ok = true;
        for (int i = (int)l; i < ngrp; i += 64)
            ok &= (__hip_atomic_load(base + i, __ATOMIC_RELAXED,
                                     __HIP_MEMORY_SCOPE_AGENT) >= tok);
        if (__all(ok)) break;
        __builtin_amdgcn_s_sleep(2);
    }
    asm volatile("buffer_inv sc0" ::: "memory");   // invalidate per-CU L1 only
}

// ---------------- wave GEMM helper ----------------
template<int MT, int NT>
__device__ __forceinline__ void wgemm(const __bf16* __restrict__ A, int lda, int mstride,
                                      const __bf16* __restrict__ B, int ldb, int nstride,
                                      int K, f32x4 (&acc)[MT][NT]) {
    int lane = threadIdx.x & 63;
    int rr = lane & 15;
    int ko = (lane >> 4) * 8;
    const __bf16* ap = A + rr * lda + ko;
    const __bf16* bp = B + rr * ldb + ko;
    #pragma unroll 2
    for (int k = 0; k < K; k += 32) {
        bf16x8 af[MT], bfr[NT];
        #pragma unroll
        for (int mt = 0; mt < MT; mt++) af[mt] = *(const bf16x8*)(ap + mt * mstride + k);
        #pragma unroll
        for (int nt = 0; nt < NT; nt++) bfr[nt] = *(const bf16x8*)(bp + nt * nstride + k);
        #pragma unroll
        for (int mt = 0; mt < MT; mt++)
            #pragma unroll
            for (int nt = 0; nt < NT; nt++)
                acc[mt][nt] = __builtin_amdgcn_mfma_f32_16x16x32_bf16(af[mt], bfr[nt], acc[mt][nt], 0, 0, 0);
    }
}

// ---------------- prep kernels ----------------

__global__ void k_zeroctl(unsigned* bar, unsigned* flags, unsigned* cnt, float* kldacc) {
    for (int i = threadIdx.x; i < 1280; i += 256) bar[i] = 0u;
    for (int i = threadIdx.x; i < 2048; i += 256) flags[i] = 0u;
    if (threadIdx.x < 8) cnt[threadIdx.x] = 0u;
    if (threadIdx.x == 0) *kldacc = 0.f;
}

__global__ void k_pack(const float* __restrict__ src, int src_ld, int col_off,
                       __bf16* __restrict__ dst, int cols, int total) {
    int i = blockIdx.x * 256 + threadIdx.x;
    if (i >= total) return;
    int r = i / cols, c = i - r * cols;
    dst[i] = (__bf16)src[r * src_ld + col_off + c];
}

__global__ void k_copyf(const float* __restrict__ s, float* __restrict__ d, int n) {
    int i = blockIdx.x * 256 + threadIdx.x;
    if (i < n) d[i] = s[i];
}

__global__ void k_px(const float* __restrict__ phi_x_w, const float* __restrict__ phi_x_b,
                     float* __restrict__ px) {
    int i = blockIdx.x * 256 + threadIdx.x;  // 64*1024
    int a = i >> 10, hh = i & 1023;
    px[i] = fmaxf(phi_x_w[hh * AA + a] + phi_x_b[hh], 0.f);
}

__global__ __launch_bounds__(256) void k_tables(const float* __restrict__ enc_w1,
                                                const float* __restrict__ wih,
                                                const float* __restrict__ px,
                                                float* __restrict__ encpx,
                                                float* __restrict__ gipx) {
    __shared__ float spx[64][65];
    int tid = threadIdx.x;
    int cg = blockIdx.x * 4 + (tid >> 6);
    int a = tid & 63;
    const float* wrow = (cg < 1024) ? (enc_w1 + cg * 2048) : (wih + (cg - 1024) * 2048);
    float sum = 0.f;
    for (int k0 = 0; k0 < 1024; k0 += 64) {
        __syncthreads();
        for (int e = tid; e < 4096; e += 256)
            spx[e >> 6][e & 63] = px[((e >> 6) << 10) + k0 + (e & 63)];
        __syncthreads();
        #pragma unroll 8
        for (int kk = 0; kk < 64; kk++) sum += wrow[k0 + kk] * spx[a][kk];
    }
    if (cg < 1024) encpx[a * 1024 + cg] = sum;
    else gipx[a * 3072 + (cg - 1024)] = sum;
}

// ---------------- persistent kernel ----------------

struct PArgs {
    const int* x; const float* eps;
    const __bf16 *WA, *W2, *WPZ, *WIH, *WHH, *WDEC, *WACT;
    const float *encpx, *gipx;
    const float *eb1, *pb1, *eb2, *pb2, *pzb, *decb, *actb, *bih, *bhh;
    float *hf0, *hf1; __bf16 *hb0, *hb1;
    __bf16 *hidcat, *zbuf, *pzbuf, *tailhid, *decbuf;
    float *gh; float *kldacc; unsigned *bar, *flags, *cnt;
    float* out;
};

__global__ __launch_bounds__(256, 1) void k_persist(PArgs a) {
    int wg = blockIdx.x;
    int tid = threadIdx.x;
    int v = tid >> 6;                // wave in WG
    int lane = tid & 63;
    int rr = lane & 15;              // fragment row
    int ko = (lane >> 4) * 8;        // fragment k-offset
    int col = lane & 15, rq = (lane >> 4) * 4;
    float kl = 0.f;
    float* hf[2] = {a.hf0, a.hf1};
    __bf16* hb[2] = {a.hb0, a.hb1};

    __shared__ float ldsC[5120];        // P1: [nh][ln(5)][mt][256]  P4: [jh][mt][g(3)][256]
    __shared__ float lds2[4][2][256];   // P2 K-split partials
    __shared__ int sh_g, sh_rank, sh_ngrp;
    __shared__ float sh_kl[4];

    // ---- XCD registration (mapping-robust grouping) ----
    if (tid == 0) {
        unsigned xcc = __builtin_amdgcn_s_getreg((31 << 11) | (0 << 6) | 20) & 7u;
        sh_g = (int)xcc;
        sh_rank = (int)atomicAdd(a.cnt + xcc, 1u);
    }
    __syncthreads();
    int g = sh_g, rank = sh_rank;
    gbar(a.bar, 0, wg);                 // counts final + cache sync
    if (tid == 0)
        sh_ngrp = (int)__hip_atomic_load(a.cnt + g, __ATOMIC_RELAXED,
                                         __HIP_MEMORY_SCOPE_AGENT);
    __syncthreads();
    int ngrp = sh_ngrp;
    int base_m = g * 32;                // this XCD's 32 batch rows
    int rot = g * 4;                    // XCD stream-order rotation (LLC spread)

    unsigned tok = 1;

    for (int t = 0; t < SS; t++) {
        int cur = t & 1, nxt = cur ^ 1;

        // ---- P1: hidcat (cols 0..2047) + gh (cols 2048..5119), K=1024 ----
        // Item: 10 n-tiles (160 cols) x both m-tiles (32 rows).
        // Wave (nh=v&1, kh=v>>1): 5 n-tiles, MT=2, K-half kh.
        // Item order rotated by g*4 across XCDs.
        for (int r = rank; r < 32; r += ngrp) {
            int item = (r + rot) & 31;
            int nh = v & 1, kh = v >> 1;
            int nt0 = item * 10 + nh * 5;
            const __bf16* ap0 = hb[cur] + (size_t)(base_m + rr) * HH + kh * 512 + ko;
            const __bf16* ap1 = ap0 + (size_t)16 * HH;
            const __bf16* bp[5];
            #pragma unroll
            for (int j = 0; j < 5; j++) {
                int n = (nt0 + j) * 16 + rr;
                bp[j] = ((n < 2048) ? (a.WA + (size_t)n * HH)
                                    : (a.WHH + (size_t)(n - 2048) * HH)) + kh * 512 + ko;
            }
            f32x4 acc[2][5] = {};
            #pragma unroll 4
            for (int k = 0; k < 512; k += 32) {
                bf16x8 a0 = *(const bf16x8*)(ap0 + k);
                bf16x8 a1 = *(const bf16x8*)(ap1 + k);
                #pragma unroll
                for (int j = 0; j < 5; j++) {
                    bf16x8 bb = *(const bf16x8*)(bp[j] + k);
                    acc[0][j] = __builtin_amdgcn_mfma_f32_16x16x32_bf16(a0, bb, acc[0][j], 0, 0, 0);
                    acc[1][j] = __builtin_amdgcn_mfma_f32_16x16x32_bf16(a1, bb, acc[1][j], 0, 0, 0);
                }
            }
            // write partials for the tiles this wave does NOT finalize
            {
                int wlo = kh ? 0 : 3, whi = kh ? 3 : 5;
                for (int j = wlo; j < whi; j++)
                    #pragma unroll
                    for (int mt = 0; mt < 2; mt++)
                        #pragma unroll
                        for (int i = 0; i < 4; i++)
                            ldsC[((nh * 5 + j) * 2 + mt) * 256 + (rq + i) * 16 + col] = acc[mt][j][i];
            }
            int xbv[2][4];
            #pragma unroll
            for (int mt = 0; mt < 2; mt++)
                #pragma unroll
                for (int i = 0; i < 4; i++)
                    xbv[mt][i] = a.x[(base_m + mt * 16 + rq + i) * SS + t];
            __syncthreads();
            // combine + epilogue for the finalized tiles
            int jlo = kh ? 3 : 0, jhi = kh ? 5 : 3;
            for (int j = jlo; j < jhi; j++) {
                #pragma unroll
                for (int mt = 0; mt < 2; mt++)
                    #pragma unroll
                    for (int i = 0; i < 4; i++)
                        acc[mt][j][i] += ldsC[((nh * 5 + j) * 2 + mt) * 256 + (rq + i) * 16 + col];
                int c0 = (nt0 + j) * 16 + col;
                if (c0 < 1024) {
                    float bias = a.eb1[c0];
                    #pragma unroll
                    for (int mt = 0; mt < 2; mt++)
                        #pragma unroll
                        for (int i = 0; i < 4; i++) {
                            int m = base_m + mt * 16 + rq + i;
                            float val = acc[mt][j][i] + bias + a.encpx[xbv[mt][i] * 1024 + c0];
                            a.hidcat[m * 2048 + c0] = (__bf16)fmaxf(val, 0.f);
                        }
                } else if (c0 < 2048) {
                    float bias = a.pb1[c0 - 1024];
                    #pragma unroll
                    for (int mt = 0; mt < 2; mt++)
                        #pragma unroll
                        for (int i = 0; i < 4; i++) {
                            int m = base_m + mt * 16 + rq + i;
                            a.hidcat[m * 2048 + c0] = (__bf16)fmaxf(acc[mt][j][i] + bias, 0.f);
                        }
                } else {
                    int gc = c0 - 2048;
                    #pragma unroll
                    for (int mt = 0; mt < 2; mt++)
                        #pragma unroll
                        for (int i = 0; i < 4; i++) {
                            int m = base_m + mt * 16 + rq + i;
                            a.gh[m * 3072 + gc] = acc[mt][j][i];
                        }
                }
            }
            __syncthreads();   // protect ldsC across r-iterations
        }
        xbar(a.flags, g, rank, ngrp, tok++);

        // ---- P2: enc/pri logits (K split over 4 waves), kld, z sample ----
        for (int r = rank; r < 32; r += ngrp) {
            int item = (r + rot) & 31;
            int mtl = item >> 4, zsl = item & 15;
            const __bf16* ae_p = a.hidcat + (size_t)(base_m + mtl * 16 + rr) * 2048 + v * 256 + ko;
            const __bf16* ap_p = ae_p + 1024;
            const __bf16* be_p = a.W2 + (size_t)(zsl * 16 + rr) * HH + v * 256 + ko;
            const __bf16* bp_p = a.W2 + (size_t)(256 + zsl * 16 + rr) * HH + v * 256 + ko;
            f32x4 ae = {0.f,0.f,0.f,0.f}, av = {0.f,0.f,0.f,0.f};
            #pragma unroll
            for (int k = 0; k < 256; k += 32) {
                ae = __builtin_amdgcn_mfma_f32_16x16x32_bf16(
                    *(const bf16x8*)(ae_p + k), *(const bf16x8*)(be_p + k), ae, 0, 0, 0);
                av = __builtin_amdgcn_mfma_f32_16x16x32_bf16(
                    *(const bf16x8*)(ap_p + k), *(const bf16x8*)(bp_p + k), av, 0, 0, 0);
            }
            #pragma unroll
            for (int i = 0; i < 4; i++) {
                int idx = (rq + i) * 16 + col;
                lds2[v][0][idx] = ae[i];
                lds2[v][1][idx] = av[i];
            }
            __syncthreads();
            {
                float e = lds2[0][0][tid] + lds2[1][0][tid] + lds2[2][0][tid] + lds2[3][0][tid];
                float pv = lds2[0][1][tid] + lds2[1][1][tid] + lds2[2][1][tid] + lds2[3][1][tid];
                int m = base_m + mtl * 16 + (tid >> 4);
                int z = zsl * 16 + (tid & 15);
                float enc = e + a.eb2[z];
                float pri = pv + a.pb2[z];
                float es = softplus_(enc), ps = softplus_(pri);
                float d = enc - pri;
                kl += 2.f * (logf(ps) - logf(es)) + (es * es + d * d) / (ps * ps) - 1.f;
                const float* epst = a.eps + (size_t)t * BB * ZZ;
                a.zbuf[m * ZZ + z] = (__bf16)(epst[m * ZZ + z] * es + enc);
            }
            __syncthreads();
        }
        xbar(a.flags, g, rank, ngrp, tok++);

        // ---- P3: pz = relu(z @ phi_z_w^T + b), K=256 ----
        for (int r = rank; r < 32; r += ngrp) {
            int item = (r + rot) & 31;
            int mt = v >> 1;
            int nt = item * 2 + (v & 1);
            const __bf16* ap = a.zbuf + (size_t)(base_m + mt * 16 + rr) * ZZ + ko;
            const __bf16* bp = a.WPZ + (size_t)(nt * 16 + rr) * ZZ + ko;
            f32x4 acc = {0.f,0.f,0.f,0.f};
            #pragma unroll
            for (int k = 0; k < ZZ; k += 32)
                acc = __builtin_amdgcn_mfma_f32_16x16x32_bf16(
                    *(const bf16x8*)(ap + k), *(const bf16x8*)(bp + k), acc, 0, 0, 0);
            int n = nt * 16 + col;
            float b = a.pzb[n];
            #pragma unroll
            for (int i = 0; i < 4; i++) {
                int m = base_m + mt * 16 + rq + i;
                a.pzbuf[m * HH + n] = (__bf16)fmaxf(acc[i] + b, 0.f);
            }
        }
        xbar(a.flags, g, rank, ngrp, tok++);

        // ---- P4: gi (3 gates) + gate math + h_new, K=1024 ----
        // Item: j-tiles {2*item, 2*item+1} x both m-tiles (rotated order).
        // Wave (jh=v&1, kh=v>>1): jt = 2*item+jh, MT=2, 3 gates, K-half kh.
        for (int r = rank; r < 32; r += ngrp) {
            int item = (r + rot) & 31;
            int jh = v & 1, kh = v >> 1;
            int jt = item * 2 + jh;
            const __bf16* ap0 = a.pzbuf + (size_t)(base_m + rr) * HH + kh * 512 + ko;
            const __bf16* ap1 = ap0 + (size_t)16 * HH;
            const __bf16* bp0 = a.WIH + (size_t)(jt * 16 + rr) * HH + kh * 512 + ko;
            const __bf16* bp1g = bp0 + (size_t)1024 * HH;
            const __bf16* bp2g = bp0 + (size_t)2048 * HH;
            f32x4 acc[2][3] = {};
            #pragma unroll 4
            for (int k = 0; k < 512; k += 32) {
                bf16x8 a0 = *(const bf16x8*)(ap0 + k);
                bf16x8 a1 = *(const bf16x8*)(ap1 + k);
                bf16x8 b0 = *(const bf16x8*)(bp0 + k);
                bf16x8 b1 = *(const bf16x8*)(bp1g + k);
                bf16x8 b2 = *(const bf16x8*)(bp2g + k);
                acc[0][0] = __builtin_amdgcn_mfma_f32_16x16x32_bf16(a0, b0, acc[0][0], 0, 0, 0);
                acc[0][1] = __builtin_amdgcn_mfma_f32_16x16x32_bf16(a0, b1, acc[0][1], 0, 0, 0);
                acc[0][2] = __builtin_amdgcn_mfma_f32_16x16x32_bf16(a0, b2, acc[0][2], 0, 0, 0);
                acc[1][0] = __builtin_amdgcn_mfma_f32_16x16x32_bf16(a1, b0, acc[1][0], 0, 0, 0);
                acc[1][1] = __builtin_amdgcn_mfma_f32_16x16x32_bf16(a1, b1, acc[1][1], 0, 0, 0);
                acc[1][2] = __builtin_amdgcn_mfma_f32_16x16x32_bf16(a1, b2, acc[1][2], 0, 0, 0);
            }
            {
                int mtW = kh ^ 1;   // mt written to LDS (not finalized by this wave)
                #pragma unroll
                for (int g3 = 0; g3 < 3; g3++)
                    #pragma unroll
                    for (int i = 0; i < 4; i++)
                        ldsC[((jh * 2 + mtW) * 3 + g3) * 256 + (rq + i) * 16 + col] = acc[mtW][g3][i];
            }
            __syncthreads();
            {
                int mt = kh;        // mt finalized by this wave
                #pragma unroll
                for (int g3 = 0; g3 < 3; g3++)
                    #pragma unroll
                    for (int i = 0; i < 4; i++)
                        acc[mt][g3][i] += ldsC[((jh * 2 + mt) * 3 + g3) * 256 + (rq + i) * 16 + col];
                int j = jt * 16 + col;
                float br = a.bih[j], bz2 = a.bih[1024 + j], bn = a.bih[2048 + j];
                float cr = a.bhh[j], cz = a.bhh[1024 + j], cn = a.bhh[2048 + j];
                #pragma unroll
                for (int i = 0; i < 4; i++) {
                    int m = base_m + mt * 16 + rq + i;
                    int xb = a.x[m * SS + t];
                    const float* gp = a.gipx + xb * 3072;
                    float gir = acc[mt][0][i] + gp[j] + br;
                    float giz = acc[mt][1][i] + gp[1024 + j] + bz2;
                    float gin = acc[mt][2][i] + gp[2048 + j] + bn;
                    float ghr = a.gh[m * 3072 + j] + cr;
                    float ghz = a.gh[m * 3072 + 1024 + j] + cz;
                    float ghn = a.gh[m * 3072 + 2048 + j] + cn;
                    float rg = sigmoid_(gir + ghr);
                    float zg = sigmoid_(giz + ghz);
                    float nn = tanhf(gin + rg * ghn);
                    float hv = (1.f - zg) * nn + zg * hf[cur][m * HH + j];
                    hf[nxt][m * HH + j] = hv;
                    hb[nxt][m * HH + j] = (__bf16)hv;
                }
            }
            __syncthreads();   // protect ldsC across r-iterations
        }
        xbar(a.flags, g, rank, ngrp, tok++);
    }

    // ---- tail (final h in buffer 0, per-XCD rows) ----
    // T1: tailhid = relu(h @ pri_w1^T + pb1), K=1024
    for (int r = rank; r < 32; r += ngrp) {
        int mt = v >> 1, nt = r * 2 + (v & 1);
        f32x4 acc[1][1] = {};
        wgemm<1, 1>(hb[0] + (size_t)(base_m + mt * 16) * HH, HH, 0,
                    a.WA + (size_t)(1024 + nt * 16) * HH, HH, 0, HH, acc);
        int n = nt * 16 + col;
        float b = a.pb1[n];
        #pragma unroll
        for (int i = 0; i < 4; i++) {
            int m = base_m + mt * 16 + rq + i;
            a.tailhid[m * HH + n] = (__bf16)fmaxf(acc[0][0][i] + b, 0.f);
        }
    }
    xbar(a.flags, g, rank, ngrp, tok++);
    // T2: pri logits -> z sample (eps[S])
    if (v == 0) {
        for (int r = rank; r < 32; r += ngrp) {
            int mtl = r >> 4, zt = r & 15;
            f32x4 apv[1][1] = {};
            wgemm<1, 1>(a.tailhid + (size_t)(base_m + mtl * 16) * HH, HH, 0,
                        a.W2 + (size_t)(256 + zt * 16) * HH, HH, 0, HH, apv);
            int z = zt * 16 + col;
            float bp = a.pb2[z];
            const float* epst = a.eps + (size_t)SS * BB * ZZ;
            #pragma unroll
            for (int i = 0; i < 4; i++) {
                int m = base_m + mtl * 16 + rq + i;
                float pri = apv[0][0][i] + bp;
                float ps = softplus_(pri);
                a.zbuf[m * ZZ + z] = (__bf16)(epst[m * ZZ + z] * ps + pri);
            }
        }
    }
    xbar(a.flags, g, rank, ngrp, tok++);
    // T3: pz, K=256
    for (int r = rank; r < 32; r += ngrp) {
        int mt = v >> 1, nt = r * 2 + (v & 1);
        f32x4 acc[1][1] = {};
        wgemm<1, 1>(a.zbuf + (size_t)(base_m + mt * 16) * ZZ, ZZ, 0,
                    a.WPZ + (size_t)(nt * 16) * ZZ, ZZ, 0, ZZ, acc);
        int n = nt * 16 + col;
        float b = a.pzb[n];
        #pragma unroll
        for (int i = 0; i < 4; i++) {
            int m = base_m + mt * 16 + rq + i;
            a.pzbuf[m * HH + n] = (__bf16)fmaxf(acc[0][0][i] + b, 0.f);
        }
    }
    xbar(a.flags, g, rank, ngrp, tok++);
    // T4: dec = relu([pz|h] @ dec_w^T + b), K=2048 in two halves
    for (int r = rank; r < 32; r += ngrp) {
        int mt = v >> 1, nt = r * 2 + (v & 1);
        f32x4 acc[1][1] = {};
        wgemm<1, 1>(a.pzbuf + (size_t)(base_m + mt * 16) * HH, HH, 0,
                    a.WDEC + (size_t)(nt * 16) * 2048, 2048, 0, HH, acc);
        wgemm<1, 1>(hb[0] + (size_t)(base_m + mt * 16) * HH, HH, 0,
                    a.WDEC + (size_t)(nt * 16) * 2048 + 1024, 2048, 0, HH, acc);
        int n = nt * 16 + col;
        float b = a.decb[n];
        #pragma unroll
        for (int i = 0; i < 4; i++) {
            int m = base_m + mt * 16 + rq + i;
            a.decbuf[m * HH + n] = (__bf16)fmaxf(acc[0][0][i] + b, 0.f);
        }
    }
    xbar(a.flags, g, rank, ngrp, tok++);
    // T5: pred = dec @ act_w^T + act_b (only slices 0..7)
    if (v == 0) {
        for (int r = rank; r < 32; r += ngrp) {
            if (r >= 8) continue;
            int mt = r >> 2, nt = r & 3;
            f32x4 acc[1][1] = {};
            wgemm<1, 1>(a.decbuf + (size_t)(base_m + mt * 16) * HH, HH, 0,
                        a.WACT + (size_t)(nt * 16) * HH, HH, 0, HH, acc);
            int n = nt * 16 + col;
            float b = a.actb[n];
            #pragma unroll
            for (int i = 0; i < 4; i++) {
                int m = base_m + mt * 16 + rq + i;
                a.out[m * AA + n] = acc[0][0][i] + b;
            }
        }
    }

    // ---- kld reduce: wave -> WG -> device atomic ----
    {
        float s = kl;
        #pragma unroll
        for (int off = 1; off < 64; off <<= 1) s += __shfl_xor(s, off);
        if (lane == 0) sh_kl[v] = s;
        __syncthreads();
        if (tid == 0) {
            float ws = sh_kl[0] + sh_kl[1] + sh_kl[2] + sh_kl[3];
            atomicAdd(a.kldacc, ws);
        }
    }
    gbar(a.bar, 1, wg);
    if (wg == 0 && tid == 0) {
        float s = __hip_atomic_load(a.kldacc, __ATOMIC_ACQUIRE, __HIP_MEMORY_SCOPE_AGENT);
        a.out[BB * AA] = 0.5f * s;
    }
}

extern "C" void kernel_launch(void* const* d_in, const int* in_sizes, int n_in,
                              void* d_out, int out_size, void* d_ws, size_t ws_size,
                              hipStream_t stream) {
    const int*   x       = (const int*)d_in[0];
    const float* h0      = (const float*)d_in[1];
    const float* eps     = (const float*)d_in[2];
    const float* phi_x_w = (const float*)d_in[3];
    const float* phi_x_b = (const float*)d_in[4];
    const float* enc_w1  = (const float*)d_in[5];
    const float* enc_b1  = (const float*)d_in[6];
    const float* enc_w2  = (const float*)d_in[7];
    const float* enc_b2  = (const float*)d_in[8];
    const float* pri_w1  = (const float*)d_in[9];
    const float* pri_b1  = (const float*)d_in[10];
    const float* pri_w2  = (const float*)d_in[11];
    const float* pri_b2  = (const float*)d_in[12];
    const float* phi_z_w = (const float*)d_in[13];
    const float* phi_z_b = (const float*)d_in[14];
    const float* dec_w   = (const float*)d_in[15];
    const float* dec_b   = (const float*)d_in[16];
    const float* act_w   = (const float*)d_in[17];
    const float* act_b   = (const float*)d_in[18];
    const float* gru_wih = (const float*)d_in[19];
    const float* gru_whh = (const float*)d_in[20];
    const float* gru_bih = (const float*)d_in[21];
    const float* gru_bhh = (const float*)d_in[22];

    char* p = (char*)d_ws;
    auto alloc = [&](size_t bytes) { char* r = p; p += (bytes + 255) & ~(size_t)255; return r; };

    __bf16* WA    = (__bf16*)alloc(2048 * 1024 * 2);
    __bf16* W2    = (__bf16*)alloc(512 * 1024 * 2);
    __bf16* WPZ   = (__bf16*)alloc(1024 * 256 * 2);
    __bf16* WIH   = (__bf16*)alloc(3072 * 1024 * 2);
    __bf16* WHH   = (__bf16*)alloc(3072 * 1024 * 2);
    __bf16* WDEC  = (__bf16*)alloc(1024 * 2048 * 2);
    __bf16* WACT  = (__bf16*)alloc(64 * 1024 * 2);
    float*  px    = (float*)alloc(64 * 1024 * 4);
    float*  encpx = (float*)alloc(64 * 1024 * 4);
    float*  gipx  = (float*)alloc(64 * 3072 * 4);
    float*  hf0   = (float*)alloc(BB * HH * 4);
    float*  hf1   = (float*)alloc(BB * HH * 4);
    __bf16* hb0   = (__bf16*)alloc(BB * HH * 2);
    __bf16* hb1   = (__bf16*)alloc(BB * HH * 2);
    __bf16* hidcat = (__bf16*)alloc(BB * 2048 * 2);
    __bf16* zbuf   = (__bf16*)alloc(BB * ZZ * 2);
    __bf16* pzbuf  = (__bf16*)alloc(BB * HH * 2);
    __bf16* tailhid = (__bf16*)alloc(BB * HH * 2);
    __bf16* decbuf  = (__bf16*)alloc(BB * HH * 2);
    float*  gh     = (float*)alloc(BB * 3072 * 4);
    unsigned* bar  = (unsigned*)alloc(1280 * 4);
    unsigned* flags = (unsigned*)alloc(2048 * 4);
    unsigned* cnt  = (unsigned*)alloc(64 * 4);
    float*  kldacc = (float*)alloc(256);

    auto pack = [&](const float* src, int src_ld, int off, __bf16* dst, int rows, int cols) {
        int total = rows * cols;
        k_pack<<<(total + 255) / 256, 256, 0, stream>>>(src, src_ld, off, dst, cols, total);
    };

    k_zeroctl<<<1, 256, 0, stream>>>(bar, flags, cnt, kldacc);
    pack(enc_w1, 2048, 1024, WA, 1024, 1024);
    pack(pri_w1, 1024, 0, WA + 1024 * 1024, 1024, 1024);
    pack(enc_w2, 1024, 0, W2, 256, 1024);
    pack(pri_w2, 1024, 0, W2 + 256 * 1024, 256, 1024);
    pack(phi_z_w, 256, 0, WPZ, 1024, 256);
    pack(gru_wih, 2048, 1024, WIH, 3072, 1024);
    pack(gru_whh, 1024, 0, WHH, 3072, 1024);
    pack(dec_w, 2048, 0, WDEC, 1024, 2048);
    pack(act_w, 1024, 0, WACT, 64, 1024);
    pack(h0, 1024, 0, hb0, 256, 1024);
    k_copyf<<<(BB * HH + 255) / 256, 256, 0, stream>>>(h0, hf0, BB * HH);
    k_px<<<(64 * 1024) / 256, 256, 0, stream>>>(phi_x_w, phi_x_b, px);
    k_tables<<<1024, 256, 0, stream>>>(enc_w1, gru_wih, px, encpx, gipx);

    PArgs pa;
    pa.x = x; pa.eps = eps;
    pa.WA = WA; pa.W2 = W2; pa.WPZ = WPZ; pa.WIH = WIH; pa.WHH = WHH;
    pa.WDEC = WDEC; pa.WACT = WACT;
    pa.encpx = encpx; pa.gipx = gipx;
    pa.eb1 = enc_b1; pa.pb1 = pri_b1; pa.eb2 = enc_b2; pa.pb2 = pri_b2;
    pa.pzb = phi_z_b; pa.decb = dec_b; pa.actb = act_b;
    pa.bih = gru_bih; pa.bhh = gru_bhh;
    pa.hf0 = hf0; pa.hf1 = hf1; pa.hb0 = hb0; pa.hb1 = hb1;
    pa.hidcat = hidcat; pa.zbuf = zbuf; pa.pzbuf = pzbuf;
    pa.tailhid = tailhid; pa.decbuf = decbuf;
    pa.gh = gh; pa.kldacc = kldacc;
    pa.bar = bar; pa.flags = flags; pa.cnt = cnt;
    pa.out = (float*)d_out;

    k_persist<<<dim3(NWG), dim3(256), 0, stream>>>(pa);
}